// Round 12
// baseline (183.357 us; speedup 1.0000x reference)
//
#include <hip/hip_runtime.h>
#include <stdint.h>

typedef int   int32x4   __attribute__((ext_vector_type(4)));
typedef int   int32x16  __attribute__((ext_vector_type(16)));
typedef float floatx4   __attribute__((ext_vector_type(4)));

#define B_ROWS 131072
#define DK 512           // K (= D)
#define FN 512           // N (= F)
#define A_SCALE_F ((float)(127.0 / 6.0))

// fused-GEMM geometry: 256 blocks x 512 threads (8 waves, 2/SIMD -> 256 VGPR).
// Wave w owns cols [w*64, w*64+64) as two 32-col panels; B lives in 128 regs.
#define GBLK 256
#define GT   512
#define BMS  32
#define GTILES (B_ROWS / BMS / GBLK)   // 16 (even, required by the 2-unroll)

// ---------------- prepass: quantize weights into B-fragment layout -------------
__global__ void wq_quant_kernel(const float* __restrict__ kern,  // [DK][FN]
                                int8_t* __restrict__ wq,         // [FN][DK]
                                float* __restrict__ invcs) {     // [FN]
  __shared__ float smax[256];
  __shared__ float sscale[4];
  const int c = threadIdx.x & 3;         // col within block
  const int g = threadIdx.x >> 2;        // row-group 0..63 (8 rows each)
  const int col = blockIdx.x * 4 + c;

  float m = 0.f;
#pragma unroll
  for (int i = 0; i < 8; ++i) {
    m = fmaxf(m, fabsf(kern[(size_t)(g * 8 + i) * FN + col]));
  }
  smax[threadIdx.x] = m;
  __syncthreads();
  if (threadIdx.x < 4) {
    float mm = smax[threadIdx.x];
#pragma unroll 8
    for (int g2 = 1; g2 < 64; ++g2) mm = fmaxf(mm, smax[g2 * 4 + threadIdx.x]);
    const float wb = fmaxf(mm, 1e-6f);
    const float ws = 127.f / wb;               // f32 divide, matches jnp w_scale
    sscale[threadIdx.x] = ws;
    invcs[blockIdx.x * 4 + threadIdx.x] =
        (float)(1.0 / ((double)A_SCALE_F * (double)ws));
  }
  __syncthreads();
  const float ws = sscale[c];
  uint32_t* wq32 = (uint32_t*)(wq + (size_t)col * DK);
#pragma unroll
  for (int d = 0; d < 2; ++d) {                // 8 rows -> 2 packed words
    uint32_t p = 0;
#pragma unroll
    for (int j = 0; j < 4; ++j) {
      float v = kern[(size_t)(g * 8 + d * 4 + j) * FN + col] * ws;
      v = floorf(v + 0.5f);                    // AQT round: floor(v+0.5)
      v = fminf(fmaxf(v, -127.f), 127.f);
      p |= ((uint32_t)((int)v & 255)) << (8 * j);
    }
    wq32[g * 2 + d] = p;
  }
}

// ---------------- fused GEMM: 2-deep prefetch, 8 waves, 256-VGPR budget --------
// (R11 structure. Single delta vs R11: the two 32-col panels share ONE K-loop —
// each A-fragment is ds_read once and feeds both MFMAs, halving LDS reads
// (256->128 ds_read_b128 per CU per tile, ~1.3us -> ~0.65us of LDS pipe time).)
__device__ __forceinline__ uint32_t quant4(floatx4 v) {
  uint32_t p = 0;
#pragma unroll
  for (int j = 0; j < 4; ++j) {
    float q = floorf(v[j] * A_SCALE_F + 0.5f);   // AQT round: floor(v+0.5)
    q = fminf(fmaxf(q, -127.f), 127.f);
    p |= ((uint32_t)((int)q & 255)) << (8 * j);
  }
  return p;
}

__global__ __launch_bounds__(GT, 2)
void aqt_gemm_fused(const float* __restrict__ x,     // [B_ROWS][DK]
                    const int8_t* __restrict__ wq,   // [FN][DK]
                    const float* __restrict__ invcs, // [FN]
                    const float* __restrict__ bias,  // [FN]
                    float* __restrict__ out) {       // [B_ROWS][FN]
  __shared__ __align__(16) uint8_t xq[2][BMS * DK];  // 2 x 16 KB

  const int tid  = threadIdx.x;
  const int lane = tid & 63;
  const int wv   = tid >> 6;       // 0..7 -> col strip w*64
  const int l31  = lane & 31;
  const int l5   = lane >> 5;

  const int c4 = tid & 127;        // float4 col within a row
  const int rg = tid >> 7;         // 0..3 -> rows rg, rg+4, ..., rg+28

  // ---- B fragments into registers, once (256 KB, L2-hot): 2 panels ----
  const int col0 = wv * 64 + l31;
  const int col1 = col0 + 32;
  int32x4 Bf0[16], Bf1[16];
#pragma unroll
  for (int ks = 0; ks < 16; ++ks) {
    Bf0[ks] = *(const int32x4*)(wq + (size_t)col0 * DK + ks * 32 + l5 * 16);
    Bf1[ks] = *(const int32x4*)(wq + (size_t)col1 * DK + ks * 32 + l5 * 16);
  }
  const float inv0 = invcs[col0], bv0 = bias[col0];
  const float inv1 = invcs[col1], bv1 = bias[col1];

  const size_t row0 = (size_t)blockIdx.x * (GTILES * BMS);

  // issue the 8 f32 tile loads for tile starting at row rt
#define LOADV(vdst, rt)                                                       \
  {                                                                           \
    const float* xg_ = x + (size_t)(rt) * DK;                                 \
    _Pragma("unroll")                                                         \
    for (int i_ = 0; i_ < 8; ++i_)                                            \
      vdst[i_] = *(const floatx4*)(xg_ + (size_t)(i_ * 4 + rg) * DK + c4 * 4);\
  }

  // quantize 8 granules into LDS buffer (XOR-swizzled)
#define QWRITE(vsrc, bufp)                                                    \
  {                                                                           \
    _Pragma("unroll")                                                         \
    for (int i_ = 0; i_ < 8; ++i_) {                                          \
      const int r_ = i_ * 4 + rg;                                             \
      *(uint32_t*)(&(bufp)[r_ * DK + ((c4 * 4) ^ ((r_ & 31) << 4))]) =        \
          quant4(vsrc[i_]);                                                   \
    }                                                                         \
  }

  // both 32-col panels in ONE K-loop: each a-fragment read once, fed to both
  // MFMAs; epilogue NT stores for both panels.
#define COMPUTE2(bufp, rt)                                                    \
  {                                                                           \
    int32x16 acc0 = (int32x16)(0);                                            \
    int32x16 acc1 = (int32x16)(0);                                            \
    const uint8_t* aRow_ = (bufp) + l31 * DK;                                 \
    _Pragma("unroll")                                                         \
    for (int ks_ = 0; ks_ < 16; ++ks_) {                                      \
      int32x4 a_ = *(const int32x4*)(aRow_ + ((ks_ * 32 + l5 * 16) ^ (l31 << 4))); \
      acc0 = __builtin_amdgcn_mfma_i32_32x32x32_i8(a_, Bf0[ks_], acc0, 0, 0, 0); \
      acc1 = __builtin_amdgcn_mfma_i32_32x32x32_i8(a_, Bf1[ks_], acc1, 0, 0, 0); \
    }                                                                         \
    _Pragma("unroll")                                                         \
    for (int r_ = 0; r_ < 16; ++r_) {                                         \
      const int rowl_ = (r_ & 3) + 8 * (r_ >> 2) + 4 * l5;                    \
      __builtin_nontemporal_store((float)acc0[r_] * inv0 + bv0,               \
                                  &out[((rt) + rowl_) * FN + col0]);          \
    }                                                                         \
    _Pragma("unroll")                                                         \
    for (int r_ = 0; r_ < 16; ++r_) {                                         \
      const int rowl_ = (r_ & 3) + 8 * (r_ >> 2) + 4 * l5;                    \
      __builtin_nontemporal_store((float)acc1[r_] * inv1 + bv1,               \
                                  &out[((rt) + rowl_) * FN + col1]);          \
    }                                                                         \
  }

  floatx4 vA[8], vB[8];

  // ---- prologue: tile 0 staged (startup stall, once); tile 1 in flight ----
  LOADV(vA, row0);
  QWRITE(vA, (&xq[0][0]));
  LOADV(vB, row0 + BMS);
  asm volatile("s_waitcnt lgkmcnt(0)" ::: "memory");
  __builtin_amdgcn_s_barrier();

#pragma unroll 1
  for (int t = 0; t < GTILES; t += 2) {
    const size_t rowT = row0 + (size_t)t * BMS;

    // even: compute buf0 (tile t); prefetch vA <- t+2; quantize vB -> buf1
    if (t + 2 < GTILES) LOADV(vA, rowT + 2 * BMS);
    COMPUTE2((&xq[0][0]), rowT);
    QWRITE(vB, (&xq[1][0]));              // tile t+1 (always < GTILES)
    asm volatile("s_waitcnt lgkmcnt(0)" ::: "memory");
    __builtin_amdgcn_s_barrier();

    // odd: compute buf1 (tile t+1); prefetch vB <- t+3; quantize vA -> buf0
    if (t + 3 < GTILES) LOADV(vB, rowT + 3 * BMS);
    COMPUTE2((&xq[1][0]), rowT + BMS);
    if (t + 2 < GTILES) QWRITE(vA, (&xq[0][0]));
    asm volatile("s_waitcnt lgkmcnt(0)" ::: "memory");
    __builtin_amdgcn_s_barrier();
  }

#undef LOADV
#undef QWRITE
#undef COMPUTE2
}

extern "C" void kernel_launch(void* const* d_in, const int* in_sizes, int n_in,
                              void* d_out, int out_size, void* d_ws, size_t ws_size,
                              hipStream_t stream) {
  const float* x    = (const float*)d_in[0];
  const float* kern = (const float*)d_in[1];
  const float* bias = (const float*)d_in[2];
  // d_in[3] = padding_mask: fixed act bounds + eval mode -> not in the math.

  int8_t* wq    = (int8_t*)d_ws;                            // 256 KB
  float*  invcs = (float*)((char*)d_ws + (size_t)FN * DK);  // 2 KB

  wq_quant_kernel<<<128, 256, 0, stream>>>(kern, wq, invcs);
  aqt_gemm_fused<<<GBLK, GT, 0, stream>>>(x, wq, invcs, bias, (float*)d_out);
}

// Round 13
// 110.878 us; speedup vs baseline: 1.6537x; 1.6537x over previous
//
#include <hip/hip_runtime.h>
#include <stdint.h>

typedef int   int32x4   __attribute__((ext_vector_type(4)));
typedef int   int32x16  __attribute__((ext_vector_type(16)));
typedef float floatx4   __attribute__((ext_vector_type(4)));

#define B_ROWS 131072
#define DK 512           // K (= D)
#define FN 512           // N (= F)
#define A_SCALE_F ((float)(127.0 / 6.0))

// fused-GEMM geometry: 512 blocks x 512 threads (8 waves). 2 blocks/CU ->
// 4 waves/SIMD: when one block sits at its barrier, the other's waves fill
// the SIMDs. Per-wave budget unchanged vs R11 (the known no-spill point).
#define GBLK 512
#define GT   512
#define BMS  32
#define GTILES (B_ROWS / BMS / GBLK)   // 8 (even, required by the 2-unroll)

// ---------------- prepass: quantize weights into B-fragment layout -------------
__global__ void wq_quant_kernel(const float* __restrict__ kern,  // [DK][FN]
                                int8_t* __restrict__ wq,         // [FN][DK]
                                float* __restrict__ invcs) {     // [FN]
  __shared__ float smax[256];
  __shared__ float sscale[4];
  const int c = threadIdx.x & 3;         // col within block
  const int g = threadIdx.x >> 2;        // row-group 0..63 (8 rows each)
  const int col = blockIdx.x * 4 + c;

  float m = 0.f;
#pragma unroll
  for (int i = 0; i < 8; ++i) {
    m = fmaxf(m, fabsf(kern[(size_t)(g * 8 + i) * FN + col]));
  }
  smax[threadIdx.x] = m;
  __syncthreads();
  if (threadIdx.x < 4) {
    float mm = smax[threadIdx.x];
#pragma unroll 8
    for (int g2 = 1; g2 < 64; ++g2) mm = fmaxf(mm, smax[g2 * 4 + threadIdx.x]);
    const float wb = fmaxf(mm, 1e-6f);
    const float ws = 127.f / wb;               // f32 divide, matches jnp w_scale
    sscale[threadIdx.x] = ws;
    invcs[blockIdx.x * 4 + threadIdx.x] =
        (float)(1.0 / ((double)A_SCALE_F * (double)ws));
  }
  __syncthreads();
  const float ws = sscale[c];
  uint32_t* wq32 = (uint32_t*)(wq + (size_t)col * DK);
#pragma unroll
  for (int d = 0; d < 2; ++d) {                // 8 rows -> 2 packed words
    uint32_t p = 0;
#pragma unroll
    for (int j = 0; j < 4; ++j) {
      float v = kern[(size_t)(g * 8 + d * 4 + j) * FN + col] * ws;
      v = floorf(v + 0.5f);                    // AQT round: floor(v+0.5)
      v = fminf(fmaxf(v, -127.f), 127.f);
      p |= ((uint32_t)((int)v & 255)) << (8 * j);
    }
    wq32[g * 2 + d] = p;
  }
}

// ---------------- fused GEMM: 2-deep prefetch, 8 waves, 256-VGPR budget --------
// (R11 structure verbatim; only GBLK/GTILES changed. Sequential panels keep a
// single acc[16] live — R12 proved two live accs spill.)
__device__ __forceinline__ uint32_t quant4(floatx4 v) {
  uint32_t p = 0;
#pragma unroll
  for (int j = 0; j < 4; ++j) {
    float q = floorf(v[j] * A_SCALE_F + 0.5f);   // AQT round: floor(v+0.5)
    q = fminf(fmaxf(q, -127.f), 127.f);
    p |= ((uint32_t)((int)q & 255)) << (8 * j);
  }
  return p;
}

__global__ __launch_bounds__(GT, 2)
void aqt_gemm_fused(const float* __restrict__ x,     // [B_ROWS][DK]
                    const int8_t* __restrict__ wq,   // [FN][DK]
                    const float* __restrict__ invcs, // [FN]
                    const float* __restrict__ bias,  // [FN]
                    float* __restrict__ out) {       // [B_ROWS][FN]
  __shared__ __align__(16) uint8_t xq[2][BMS * DK];  // 2 x 16 KB

  const int tid  = threadIdx.x;
  const int lane = tid & 63;
  const int wv   = tid >> 6;       // 0..7 -> col strip w*64
  const int l31  = lane & 31;
  const int l5   = lane >> 5;

  const int c4 = tid & 127;        // float4 col within a row
  const int rg = tid >> 7;         // 0..3 -> rows rg, rg+4, ..., rg+28

  // ---- B fragments into registers, once (256 KB, L2-hot): 2 panels ----
  const int col0 = wv * 64 + l31;
  const int col1 = col0 + 32;
  int32x4 Bf0[16], Bf1[16];
#pragma unroll
  for (int ks = 0; ks < 16; ++ks) {
    Bf0[ks] = *(const int32x4*)(wq + (size_t)col0 * DK + ks * 32 + l5 * 16);
    Bf1[ks] = *(const int32x4*)(wq + (size_t)col1 * DK + ks * 32 + l5 * 16);
  }
  const float inv0 = invcs[col0], bv0 = bias[col0];
  const float inv1 = invcs[col1], bv1 = bias[col1];

  const size_t row0 = (size_t)blockIdx.x * (GTILES * BMS);

  // issue the 8 f32 tile loads for tile starting at row rt
#define LOADV(vdst, rt)                                                       \
  {                                                                           \
    const float* xg_ = x + (size_t)(rt) * DK;                                 \
    _Pragma("unroll")                                                         \
    for (int i_ = 0; i_ < 8; ++i_)                                            \
      vdst[i_] = *(const floatx4*)(xg_ + (size_t)(i_ * 4 + rg) * DK + c4 * 4);\
  }

  // quantize 8 granules into LDS buffer (XOR-swizzled)
#define QWRITE(vsrc, bufp)                                                    \
  {                                                                           \
    _Pragma("unroll")                                                         \
    for (int i_ = 0; i_ < 8; ++i_) {                                          \
      const int r_ = i_ * 4 + rg;                                             \
      *(uint32_t*)(&(bufp)[r_ * DK + ((c4 * 4) ^ ((r_ & 31) << 4))]) =        \
          quant4(vsrc[i_]);                                                   \
    }                                                                         \
  }

  // one 32-col panel: K-loop + epilogue NT stores (acc lives only inside)
#define PANEL(Bf, colv, invv, bvv, bufp, rt)                                  \
  {                                                                           \
    int32x16 acc = (int32x16)(0);                                             \
    const uint8_t* aRow_ = (bufp) + l31 * DK;                                 \
    _Pragma("unroll")                                                         \
    for (int ks_ = 0; ks_ < 16; ++ks_) {                                      \
      int32x4 a_ = *(const int32x4*)(aRow_ + ((ks_ * 32 + l5 * 16) ^ (l31 << 4))); \
      acc = __builtin_amdgcn_mfma_i32_32x32x32_i8(a_, Bf[ks_], acc, 0, 0, 0); \
    }                                                                         \
    _Pragma("unroll")                                                         \
    for (int r_ = 0; r_ < 16; ++r_) {                                         \
      const int rowl_ = (r_ & 3) + 8 * (r_ >> 2) + 4 * l5;                    \
      __builtin_nontemporal_store((float)acc[r_] * (invv) + (bvv),            \
                                  &out[((rt) + rowl_) * FN + (colv)]);        \
    }                                                                         \
  }

  floatx4 vA[8], vB[8];

  // ---- prologue: tile 0 staged (startup stall, once); tile 1 in flight ----
  LOADV(vA, row0);
  QWRITE(vA, (&xq[0][0]));
  LOADV(vB, row0 + BMS);
  asm volatile("s_waitcnt lgkmcnt(0)" ::: "memory");
  __builtin_amdgcn_s_barrier();

#pragma unroll 1
  for (int t = 0; t < GTILES; t += 2) {
    const size_t rowT = row0 + (size_t)t * BMS;

    // even: compute buf0 (tile t); prefetch vA <- t+2; quantize vB -> buf1
    if (t + 2 < GTILES) LOADV(vA, rowT + 2 * BMS);
    PANEL(Bf0, col0, inv0, bv0, (&xq[0][0]), rowT);
    PANEL(Bf1, col1, inv1, bv1, (&xq[0][0]), rowT);
    QWRITE(vB, (&xq[1][0]));              // tile t+1 (always < GTILES)
    asm volatile("s_waitcnt lgkmcnt(0)" ::: "memory");
    __builtin_amdgcn_s_barrier();

    // odd: compute buf1 (tile t+1); prefetch vB <- t+3; quantize vA -> buf0
    if (t + 3 < GTILES) LOADV(vB, rowT + 3 * BMS);
    PANEL(Bf0, col0, inv0, bv0, (&xq[1][0]), rowT + BMS);
    PANEL(Bf1, col1, inv1, bv1, (&xq[1][0]), rowT + BMS);
    if (t + 2 < GTILES) QWRITE(vA, (&xq[0][0]));
    asm volatile("s_waitcnt lgkmcnt(0)" ::: "memory");
    __builtin_amdgcn_s_barrier();
  }

#undef LOADV
#undef QWRITE
#undef PANEL
}

extern "C" void kernel_launch(void* const* d_in, const int* in_sizes, int n_in,
                              void* d_out, int out_size, void* d_ws, size_t ws_size,
                              hipStream_t stream) {
  const float* x    = (const float*)d_in[0];
  const float* kern = (const float*)d_in[1];
  const float* bias = (const float*)d_in[2];
  // d_in[3] = padding_mask: fixed act bounds + eval mode -> not in the math.

  int8_t* wq    = (int8_t*)d_ws;                            // 256 KB
  float*  invcs = (float*)((char*)d_ws + (size_t)FN * DK);  // 2 KB

  wq_quant_kernel<<<128, 256, 0, stream>>>(kern, wq, invcs);
  aqt_gemm_fused<<<GBLK, GT, 0, stream>>>(x, wq, invcs, bias, (float*)d_out);
}